// Round 1
// baseline (392.122 us; speedup 1.0000x reference)
//
#include <hip/hip_runtime.h>
#include <hip/hip_bf16.h>
#include <stdint.h>

#define N_PTS 16384
#define M_PTS 2048

#define GLOBAL_AS __attribute__((address_space(1)))
#define LDS_AS    __attribute__((address_space(3)))

typedef __bf16 bf16x8 __attribute__((ext_vector_type(8)));
typedef float  f32x4  __attribute__((ext_vector_type(4)));

// ---------------------------------------------------------------------------
// Kernel 1: K[i][j] = exp(-||x_i - z_j||_1)  -> bf16
// grid (M/256, N), block 256. x-row is block-uniform (L1 broadcast),
// design_points (32 KB) is L1/L2 resident, K written coalesced 2B/lane.
// ---------------------------------------------------------------------------
__global__ __launch_bounds__(256) void laplace_k(
    const float* __restrict__ x, const float* __restrict__ z,
    __hip_bfloat16* __restrict__ Kout) {
  const int j = blockIdx.x * 256 + threadIdx.x;
  const int i = blockIdx.y;
  const float4 xv = *reinterpret_cast<const float4*>(x + (size_t)i * 4);
  const float4 zv = *reinterpret_cast<const float4*>(z + (size_t)j * 4);
  const float l1 = fabsf(xv.x - zv.x) + fabsf(xv.y - zv.y) +
                   fabsf(xv.z - zv.z) + fabsf(xv.w - zv.w);
  Kout[(size_t)i * M_PTS + j] = __float2bfloat16(__expf(-l1));
}

// ---------------------------------------------------------------------------
// Kernel 2: Bt[j][k] = chol_inv[k][j] -> bf16 (tiled transpose, both sides
// coalesced). grid (M/32, M/32), block (32, 8).
// ---------------------------------------------------------------------------
__global__ __launch_bounds__(256) void transpose_cast(
    const float* __restrict__ B, __hip_bfloat16* __restrict__ Bt) {
  __shared__ float tile[32][33];
  const int bj = blockIdx.x * 32;  // column of B
  const int bk = blockIdx.y * 32;  // row of B
  const int tx = threadIdx.x, ty = threadIdx.y;
#pragma unroll
  for (int yy = ty; yy < 32; yy += 8)
    tile[yy][tx] = B[(size_t)(bk + yy) * M_PTS + bj + tx];
  __syncthreads();
#pragma unroll
  for (int yy = ty; yy < 32; yy += 8)
    Bt[(size_t)(bj + yy) * M_PTS + bk + tx] = __float2bfloat16(tile[tx][yy]);
}

// ---------------------------------------------------------------------------
// Kernel 3: C[i][j] = sum_k K[i][k] * chol_inv[k][j]   (fp32 out)
// m97 structure: 128x128 tile, BK=32, 256 threads (4 waves, 2x2 wave grid,
// each wave 64x64 = 4x4 frags of 16x16), global_load_lds width-16 staging
// into linear LDS (dest = tid*16, satisfying the wave-uniform-base rule).
// ---------------------------------------------------------------------------
__global__ __launch_bounds__(256) void gemm_bf16(
    const __hip_bfloat16* __restrict__ A,   // [N_PTS][M_PTS] bf16 (K matrix)
    const __hip_bfloat16* __restrict__ Bt,  // [M_PTS][M_PTS] bf16, Bt[j][k]
    float* __restrict__ Cmat) {             // [N_PTS][M_PTS] fp32
  __shared__ alignas(16) __hip_bfloat16 Alds[128][32];
  __shared__ alignas(16) __hip_bfloat16 Blds[128][32];

  const int tid  = threadIdx.x;
  const int lane = tid & 63;
  const int wave = tid >> 6;
  const int iBase = blockIdx.y * 128;
  const int jBase = blockIdx.x * 128;
  const int wr = (wave >> 1) * 64;   // wave row offset in tile
  const int wc = (wave & 1) * 64;    // wave col offset in tile
  const int q = lane >> 4;           // 0..3
  const int r = lane & 15;           // 0..15

  f32x4 acc[4][4] = {};

  // Staging map: thread t covers bf16 elements [t*8 .. t*8+7] of the 128x32
  // tile (row = t/4, col = (t%4)*8); LDS byte offset = t*16 (linear).
  const int srow = tid >> 2;
  const int scol = (tid & 3) * 8;
  const __hip_bfloat16* ag0 = A  + (size_t)(iBase + srow)      * M_PTS + scol;
  const __hip_bfloat16* ag1 = A  + (size_t)(iBase + srow + 64) * M_PTS + scol;
  const __hip_bfloat16* bg0 = Bt + (size_t)(jBase + srow)      * M_PTS + scol;
  const __hip_bfloat16* bg1 = Bt + (size_t)(jBase + srow + 64) * M_PTS + scol;

  char* aldsB = (char*)(&Alds[0][0]) + tid * 16;
  char* bldsB = (char*)(&Blds[0][0]) + tid * 16;

  for (int k0 = 0; k0 < M_PTS; k0 += 32) {
    __builtin_amdgcn_global_load_lds((const GLOBAL_AS void*)(ag0 + k0),
                                     (LDS_AS void*)(aldsB),        16, 0, 0);
    __builtin_amdgcn_global_load_lds((const GLOBAL_AS void*)(ag1 + k0),
                                     (LDS_AS void*)(aldsB + 4096), 16, 0, 0);
    __builtin_amdgcn_global_load_lds((const GLOBAL_AS void*)(bg0 + k0),
                                     (LDS_AS void*)(bldsB),        16, 0, 0);
    __builtin_amdgcn_global_load_lds((const GLOBAL_AS void*)(bg1 + k0),
                                     (LDS_AS void*)(bldsB + 4096), 16, 0, 0);
    __syncthreads();  // compiler drains vmcnt before s_barrier

    bf16x8 af[4], bfr[4];
#pragma unroll
    for (int m = 0; m < 4; ++m)
      af[m] = *reinterpret_cast<const bf16x8*>(&Alds[wr + m * 16 + r][q * 8]);
#pragma unroll
    for (int n = 0; n < 4; ++n)
      bfr[n] = *reinterpret_cast<const bf16x8*>(&Blds[wc + n * 16 + r][q * 8]);

#pragma unroll
    for (int m = 0; m < 4; ++m)
#pragma unroll
      for (int n = 0; n < 4; ++n)
        acc[m][n] = __builtin_amdgcn_mfma_f32_16x16x32_bf16(
            af[m], bfr[n], acc[m][n], 0, 0, 0);
    __syncthreads();
  }

  // Epilogue: C/D layout col = lane&15, row = (lane>>4)*4 + reg  [m89]
  const int crow = iBase + wr + q * 4;
  const int ccol = jBase + wc + r;
#pragma unroll
  for (int m = 0; m < 4; ++m)
#pragma unroll
    for (int n = 0; n < 4; ++n)
#pragma unroll
      for (int v = 0; v < 4; ++v)
        Cmat[(size_t)(crow + m * 16 + v) * M_PTS + (ccol + n * 16)] =
            acc[m][n][v];
}

extern "C" void kernel_launch(void* const* d_in, const int* in_sizes, int n_in,
                              void* d_out, int out_size, void* d_ws,
                              size_t ws_size, hipStream_t stream) {
  const float* x    = (const float*)d_in[0];
  const float* z    = (const float*)d_in[1];
  const float* chol = (const float*)d_in[2];
  float* out = (float*)d_out;

  __hip_bfloat16* Kbf = (__hip_bfloat16*)d_ws;                       // 64 MB
  __hip_bfloat16* Bt  = (__hip_bfloat16*)((char*)d_ws +
                        (size_t)N_PTS * M_PTS * sizeof(__hip_bfloat16)); // 8 MB

  laplace_k<<<dim3(M_PTS / 256, N_PTS), 256, 0, stream>>>(x, z, Kbf);
  transpose_cast<<<dim3(M_PTS / 32, M_PTS / 32), dim3(32, 8), 0, stream>>>(
      chol, Bt);
  gemm_bf16<<<dim3(M_PTS / 128, N_PTS / 128), 256, 0, stream>>>(Kbf, Bt, out);
}

// Round 2
// 275.895 us; speedup vs baseline: 1.4213x; 1.4213x over previous
//
#include <hip/hip_runtime.h>
#include <hip/hip_bf16.h>
#include <stdint.h>

#define N_PTS 16384
#define M_PTS 2048

#define GLOBAL_AS __attribute__((address_space(1)))
#define LDS_AS    __attribute__((address_space(3)))

typedef __bf16 bf16x8 __attribute__((ext_vector_type(8)));
typedef float  f32x4  __attribute__((ext_vector_type(4)));

// ---------------------------------------------------------------------------
// Kernel 1: K[i][j] = exp(-||x_i - z_j||_1)  -> bf16, vectorized 8/thread.
// One block per row i; thread t covers j = t*8 .. t*8+7. z (32 KB) is
// L1-resident; x row is a block-uniform broadcast; store is bf16x8 (16 B).
// ---------------------------------------------------------------------------
__global__ __launch_bounds__(256) void laplace_k(
    const float* __restrict__ x, const float* __restrict__ z,
    __hip_bfloat16* __restrict__ Kout) {
  const int i = blockIdx.x;
  const int t = threadIdx.x;
  const float4 xv = *reinterpret_cast<const float4*>(x + (size_t)i * 4);
  const float4* zp = reinterpret_cast<const float4*>(z) + (size_t)t * 8;
  bf16x8 outv;
#pragma unroll
  for (int u = 0; u < 8; ++u) {
    const float4 zv = zp[u];
    const float l1 = fabsf(xv.x - zv.x) + fabsf(xv.y - zv.y) +
                     fabsf(xv.z - zv.z) + fabsf(xv.w - zv.w);
    outv[u] = (__bf16)__expf(-l1);  // clang cvt f32->bf16 is RNE
  }
  *reinterpret_cast<bf16x8*>(Kout + (size_t)i * M_PTS + (size_t)t * 8) = outv;
}

// ---------------------------------------------------------------------------
// Kernel 2: Bt[j][k] = chol_inv[k][j] -> bf16 (tiled transpose).
// ---------------------------------------------------------------------------
__global__ __launch_bounds__(256) void transpose_cast(
    const float* __restrict__ B, __hip_bfloat16* __restrict__ Bt) {
  __shared__ float tile[32][33];
  const int bj = blockIdx.x * 32;
  const int bk = blockIdx.y * 32;
  const int tx = threadIdx.x, ty = threadIdx.y;
#pragma unroll
  for (int yy = ty; yy < 32; yy += 8)
    tile[yy][tx] = B[(size_t)(bk + yy) * M_PTS + bj + tx];
  __syncthreads();
#pragma unroll
  for (int yy = ty; yy < 32; yy += 8)
    Bt[(size_t)(bj + yy) * M_PTS + bk + tx] = __float2bfloat16(tile[tx][yy]);
}

// ---------------------------------------------------------------------------
// Kernel 3: C = K @ U, exploiting upper-triangular U: column-tile jt only
// needs k < (jt+1)*128. 128x128 tile, BK=32, 4 waves, 16x16x32 MFMA.
// T3-minimum 2-phase pipeline: double-buffered LDS, prefetch next K-tile
// via global_load_lds BEFORE ds_read+MFMA of current, ONE raw s_barrier +
// vmcnt(0) per K-step (not __syncthreads' double drain).
// Block swizzle: bid%8 -> XCD; within an XCD, 16 consecutive blocks share
// one B-panel (jt), jt descending so heavy (long-K) tiles dispatch first;
// every XCD gets every jt -> balanced triangular work.
// ---------------------------------------------------------------------------
__global__ __launch_bounds__(256) void gemm_bf16(
    const __hip_bfloat16* __restrict__ A,   // [N_PTS][M_PTS] bf16 (K matrix)
    const __hip_bfloat16* __restrict__ Bt,  // [M_PTS][M_PTS] bf16, Bt[j][k]
    float* __restrict__ Cmat) {             // [N_PTS][M_PTS] fp32
  __shared__ alignas(16) __hip_bfloat16 Alds[2][128][32];
  __shared__ alignas(16) __hip_bfloat16 Blds[2][128][32];

  const int tid  = threadIdx.x;
  const int lane = tid & 63;
  const int wave = tid >> 6;

  // --- block swizzle: bid -> (xcd, n) -> (jt heavy-first, it) ---
  const int bid = blockIdx.x;
  const int xcd = bid & 7;
  const int n   = bid >> 3;                 // 0..255 per XCD
  const int jt  = 15 - (n >> 4);            // 16 j-tiles, heavy first
  const int it  = (xcd << 4) | (n & 15);    // 0..127
  const int iBase = it * 128;
  const int jBase = jt * 128;
  const int kLimit = jBase + 128;           // triangular bound (exact)

  const int wr = (wave >> 1) * 64;
  const int wc = (wave & 1) * 64;
  const int q = lane >> 4;
  const int r = lane & 15;

  f32x4 acc[4][4] = {};

  // staging map: thread t covers 8 bf16 at (row=t/4, col=(t%4)*8) of 128x32
  const int srow = tid >> 2;
  const int scol = (tid & 3) * 8;
  const __hip_bfloat16* ag0 = A  + (size_t)(iBase + srow)      * M_PTS + scol;
  const __hip_bfloat16* ag1 = A  + (size_t)(iBase + srow + 64) * M_PTS + scol;
  const __hip_bfloat16* bg0 = Bt + (size_t)(jBase + srow)      * M_PTS + scol;
  const __hip_bfloat16* bg1 = Bt + (size_t)(jBase + srow + 64) * M_PTS + scol;

  char* aldsB = (char*)(&Alds[0][0][0]) + tid * 16;
  char* bldsB = (char*)(&Blds[0][0][0]) + tid * 16;

#define STAGE(b, k0)                                                          \
  do {                                                                        \
    __builtin_amdgcn_global_load_lds((const GLOBAL_AS void*)(ag0 + (k0)),     \
                                     (LDS_AS void*)(aldsB + (b)*8192), 16, 0, 0); \
    __builtin_amdgcn_global_load_lds((const GLOBAL_AS void*)(ag1 + (k0)),     \
                                     (LDS_AS void*)(aldsB + (b)*8192 + 4096), 16, 0, 0); \
    __builtin_amdgcn_global_load_lds((const GLOBAL_AS void*)(bg0 + (k0)),     \
                                     (LDS_AS void*)(bldsB + (b)*8192), 16, 0, 0); \
    __builtin_amdgcn_global_load_lds((const GLOBAL_AS void*)(bg1 + (k0)),     \
                                     (LDS_AS void*)(bldsB + (b)*8192 + 4096), 16, 0, 0); \
  } while (0)

  // prologue
  STAGE(0, 0);
  asm volatile("s_waitcnt vmcnt(0)" ::: "memory");
  __builtin_amdgcn_s_barrier();

  int cur = 0;
  for (int k0 = 0; k0 < kLimit; k0 += 32) {
    const int nxt = k0 + 32;
    if (nxt < kLimit) STAGE(cur ^ 1, nxt);  // prefetch overlaps MFMA below

    bf16x8 af[4], bfr[4];
#pragma unroll
    for (int m = 0; m < 4; ++m)
      af[m] = *reinterpret_cast<const bf16x8*>(&Alds[cur][wr + m * 16 + r][q * 8]);
#pragma unroll
    for (int nn = 0; nn < 4; ++nn)
      bfr[nn] = *reinterpret_cast<const bf16x8*>(&Blds[cur][wc + nn * 16 + r][q * 8]);

#pragma unroll
    for (int m = 0; m < 4; ++m)
#pragma unroll
      for (int nn = 0; nn < 4; ++nn)
        acc[m][nn] = __builtin_amdgcn_mfma_f32_16x16x32_bf16(
            af[m], bfr[nn], acc[m][nn], 0, 0, 0);

    asm volatile("s_waitcnt vmcnt(0)" ::: "memory");  // next tile staged
    __builtin_amdgcn_s_barrier();                     // all reads of cur done
    cur ^= 1;
  }
#undef STAGE

  // Epilogue: C/D layout col = lane&15, row = (lane>>4)*4 + reg  [m89]
  const int crow = iBase + wr + q * 4;
  const int ccol = jBase + wc + r;
#pragma unroll
  for (int m = 0; m < 4; ++m)
#pragma unroll
    for (int nn = 0; nn < 4; ++nn)
#pragma unroll
      for (int v = 0; v < 4; ++v)
        Cmat[(size_t)(crow + m * 16 + v) * M_PTS + (ccol + nn * 16)] =
            acc[m][nn][v];
}

extern "C" void kernel_launch(void* const* d_in, const int* in_sizes, int n_in,
                              void* d_out, int out_size, void* d_ws,
                              size_t ws_size, hipStream_t stream) {
  const float* x    = (const float*)d_in[0];
  const float* z    = (const float*)d_in[1];
  const float* chol = (const float*)d_in[2];
  float* out = (float*)d_out;

  __hip_bfloat16* Kbf = (__hip_bfloat16*)d_ws;                        // 64 MB
  __hip_bfloat16* Bt  = (__hip_bfloat16*)((char*)d_ws +
                        (size_t)N_PTS * M_PTS * sizeof(__hip_bfloat16)); // 8 MB

  laplace_k<<<dim3(N_PTS), 256, 0, stream>>>(x, z, Kbf);
  transpose_cast<<<dim3(M_PTS / 32, M_PTS / 32), dim3(32, 8), 0, stream>>>(
      chol, Bt);
  gemm_bf16<<<dim3((M_PTS / 128) * (N_PTS / 128)), 256, 0, stream>>>(
      Kbf, Bt, out);
}

// Round 4
// 232.561 us; speedup vs baseline: 1.6861x; 1.1863x over previous
//
#include <hip/hip_runtime.h>
#include <hip/hip_bf16.h>
#include <stdint.h>

#define N_PTS 16384
#define M_PTS 2048

#define GLOBAL_AS __attribute__((address_space(1)))
#define LDS_AS    __attribute__((address_space(3)))

typedef __bf16 bf16x8 __attribute__((ext_vector_type(8)));
typedef float  f32x4  __attribute__((ext_vector_type(4)));

// ---------------------------------------------------------------------------
// Kernel 1: K[i][j] = exp(-||x_i - z_j||_1) -> bf16. COALESCED: thread t
// handles j = u*256+t, u=0..7. z float4 loads are lane-consecutive (1 KB/wave
// per load); stores are 128 B/wave contiguous. x row is block-uniform.
// ---------------------------------------------------------------------------
__global__ __launch_bounds__(256) void laplace_k(
    const float* __restrict__ x, const float* __restrict__ z,
    __hip_bfloat16* __restrict__ Kout) {
  const int i = blockIdx.x;
  const int t = threadIdx.x;
  const float4 xv = *reinterpret_cast<const float4*>(x + (size_t)i * 4);
#pragma unroll
  for (int u = 0; u < 8; ++u) {
    const int j = u * 256 + t;
    const float4 zv = reinterpret_cast<const float4*>(z)[j];
    const float l1 = fabsf(xv.x - zv.x) + fabsf(xv.y - zv.y) +
                     fabsf(xv.z - zv.z) + fabsf(xv.w - zv.w);
    Kout[(size_t)i * M_PTS + j] = __float2bfloat16(__expf(-l1));
  }
}

// ---------------------------------------------------------------------------
// Kernel 2: Bt[j][k] = chol_inv[k][j] -> bf16 (tiled transpose).
// ---------------------------------------------------------------------------
__global__ __launch_bounds__(256) void transpose_cast(
    const float* __restrict__ B, __hip_bfloat16* __restrict__ Bt) {
  __shared__ float tile[32][33];
  const int bj = blockIdx.x * 32;
  const int bk = blockIdx.y * 32;
  const int tx = threadIdx.x, ty = threadIdx.y;
#pragma unroll
  for (int yy = ty; yy < 32; yy += 8)
    tile[yy][tx] = B[(size_t)(bk + yy) * M_PTS + bj + tx];
  __syncthreads();
#pragma unroll
  for (int yy = ty; yy < 32; yy += 8)
    Bt[(size_t)(bj + yy) * M_PTS + bk + tx] = __float2bfloat16(tile[tx][yy]);
}

// ---------------------------------------------------------------------------
// Kernel 3: C = K @ U (triangular), 256x256 tile, BK=64, 8 waves (2Mx4N),
// 8-phase schedule (T2 swizzle + T3/T4 counted vmcnt + T5 setprio).
//
// LDS 128 KiB: [buf(2)][A|B][half(2)][128 rows][64 k] bf16.
//   A half h = rows iBase+h*128..+127;  B half h = cols jBase+h*128..+127.
// Swizzle (T2, both-sides per rule 21): LDS[row][colb] holds global column
//   byte colb ^ ((row&7)<<4). Writer: global_load_lds dest LINEAR
//   (l*8192 + tid*16 => row = l*64+tid/8, colb=(tid&7)*16), source column
//   pre-swizzled: scolE = 8*((tid&7)^((tid>>3)&7)). Reader XORs the same.
//
// Phase p of a tile reads A-quadrant q=p-1 (rows q*32..+31 of the wave's
// half, 4 ds_read_b128) ; p=1 additionally reads all 8 B frags (12 reads).
// Stage ledger (frame computes tiles t@buf0 P1-4, t+1@buf1 P5-8; regions
// free strictly after the trailing barrier of their last-read phase):
//   P1: A0(t+1)->buf1  [buf1.A read last in prev P8]
//   P2: A1(t+1)->buf1 ; B0(t+2)->buf0  [buf0.B fully read in P1]
//   P3: B1(t+2)->buf0
//   P4: vmcnt(4): leaves B(t+2) (4 loads) in flight, guarantees A(t+1)
//       landed -> tile t+1 complete before P5.   (last frame: vmcnt(0))
//   P5: A0(t+2)->buf0  [buf0.A fully read by P4]
//   P6: A1(t+2)->buf0 ; B0(t+3)->buf1  [buf1.B fully read in P5]
//   P7: B1(t+3)->buf1
//   P8: vmcnt(4): leaves B(t+3) in flight, tile t+2 complete before next P1.
// Per phase: reads; stages; s_barrier; lgkmcnt(0); sched_barrier(0) [rule
// 18]; setprio(1); 16 MFMA; setprio(0); s_barrier.
//
// Triangular balance: bids 0-255 -> jt=7..4 (heavy), 256-511 -> jt=0..3 so
// a CU's two sequential blocks sum to constant work (jt+1 pairs = 9).
// ---------------------------------------------------------------------------
__global__ __launch_bounds__(512, 2) void gemm_bf16_8ph(
    const __hip_bfloat16* __restrict__ A,   // [N][2048] bf16 (K matrix)
    const __hip_bfloat16* __restrict__ Bt,  // [2048][2048] bf16, Bt[j][k]
    float* __restrict__ Cmat) {             // [N][2048] fp32
  __shared__ alignas(16) char ldsBuf[131072];
  char* ldsC = ldsBuf;

  const int tid  = threadIdx.x;
  const int lane = tid & 63;
  const int wid  = tid >> 6;  // 0..7
  const int wm   = wid >> 2;  // 0..1 -> A half / row block
  const int wn   = wid & 3;   // 0..3 -> 64-col block
  const int q    = lane >> 4;
  const int r    = lane & 15;

  const int bid = blockIdx.x;
  int it, jt;
  if (bid < 256) { jt = 7 - (bid >> 6); it = bid & 63; }
  else           { jt = (bid - 256) >> 6; it = (bid - 256) & 63; }
  const int iBase = it * 256;
  const int jBase = jt * 256;
  const int NT = (jBase + 256) >> 6;  // K-tiles of 64; 4..32, mult of 4

  // ---- staging source pointers (pre-swizzled column, rule 21) ----
  const int srow  = tid >> 3;
  const int scolE = ((tid & 7) ^ ((tid >> 3) & 7)) * 8;
  const __hip_bfloat16* aGp0 = A  + (size_t)(iBase + srow)       * M_PTS + scolE;
  const __hip_bfloat16* aGp1 = A  + (size_t)(iBase + 128 + srow) * M_PTS + scolE;
  const __hip_bfloat16* bGp0 = Bt + (size_t)(jBase + srow)       * M_PTS + scolE;
  const __hip_bfloat16* bGp1 = Bt + (size_t)(jBase + 128 + srow) * M_PTS + scolE;

  // ---- LDS read bases (swizzled), kk=0 / kk=1 variants ----
  const int colK0 = (q * 16) ^ ((r & 7) << 4);
  const char* aRd0 = ldsC + wm * 16384 + r * 128 + colK0;
  const char* aRd1 = ldsC + wm * 16384 + r * 128 + (colK0 ^ 64);
  const char* bRd0 = ldsC + 32768 + (wn >> 1) * 16384 +
                     ((wn & 1) * 64 + r) * 128 + colK0;
  const char* bRd1 = ldsC + 32768 + (wn >> 1) * 16384 +
                     ((wn & 1) * 64 + r) * 128 + (colK0 ^ 64);

  f32x4 acc[8][4] = {};
  bf16x8 bF[4][2];

#define STG(GP, LOFF, KT)                                                    \
  do {                                                                       \
    __builtin_amdgcn_global_load_lds(                                        \
        (const GLOBAL_AS void*)((GP) + (size_t)(KT)*64),                     \
        (LDS_AS void*)(ldsC + (LOFF) + tid * 16), 16, 0, 0);                 \
    __builtin_amdgcn_global_load_lds(                                        \
        (const GLOBAL_AS void*)((GP) + (size_t)(KT)*64 + 64 * M_PTS),        \
        (LDS_AS void*)(ldsC + (LOFF) + 8192 + tid * 16), 16, 0, 0);          \
  } while (0)
// A half H in buf B0/1: LOFF = buf*65536 + H*16384 ; B: + 32768
#define STG_A0(BUF, KT) STG(aGp0, (BUF)*65536, KT)
#define STG_A1(BUF, KT) STG(aGp1, (BUF)*65536 + 16384, KT)
#define STG_B0(BUF, KT) STG(bGp0, (BUF)*65536 + 32768, KT)
#define STG_B1(BUF, KT) STG(bGp1, (BUF)*65536 + 49152, KT)

#define VM4 asm volatile("s_waitcnt vmcnt(4)" ::: "memory")
#define VM0 asm volatile("s_waitcnt vmcnt(0)" ::: "memory")
#define VMNONE (void)0

#define PHASE(Q2, BOFF, READB, VMW, ...)                                     \
  {                                                                          \
    if (READB) {                                                             \
      _Pragma("unroll") for (int nn = 0; nn < 4; ++nn) {                     \
        bF[nn][0] = *(const bf16x8*)(bRd0 + (BOFF) + nn * 2048);             \
        bF[nn][1] = *(const bf16x8*)(bRd1 + (BOFF) + nn * 2048);             \
      }                                                                      \
    }                                                                        \
    bf16x8 aF0k0 = *(const bf16x8*)(aRd0 + (BOFF) + (Q2 * 2) * 2048);        \
    bf16x8 aF0k1 = *(const bf16x8*)(aRd1 + (BOFF) + (Q2 * 2) * 2048);        \
    bf16x8 aF1k0 = *(const bf16x8*)(aRd0 + (BOFF) + (Q2 * 2 + 1) * 2048);    \
    bf16x8 aF1k1 = *(const bf16x8*)(aRd1 + (BOFF) + (Q2 * 2 + 1) * 2048);    \
    __VA_ARGS__;                                                             \
    VMW;                                                                     \
    __builtin_amdgcn_s_barrier();                                            \
    asm volatile("s_waitcnt lgkmcnt(0)" ::: "memory");                       \
    __builtin_amdgcn_sched_barrier(0);                                       \
    __builtin_amdgcn_s_setprio(1);                                           \
    _Pragma("unroll") for (int nn = 0; nn < 4; ++nn) {                       \
      acc[Q2 * 2][nn] = __builtin_amdgcn_mfma_f32_16x16x32_bf16(             \
          aF0k0, bF[nn][0], acc[Q2 * 2][nn], 0, 0, 0);                       \
      acc[Q2 * 2][nn] = __builtin_amdgcn_mfma_f32_16x16x32_bf16(             \
          aF0k1, bF[nn][1], acc[Q2 * 2][nn], 0, 0, 0);                       \
      acc[Q2 * 2 + 1][nn] = __builtin_amdgcn_mfma_f32_16x16x32_bf16(         \
          aF1k0, bF[nn][0], acc[Q2 * 2 + 1][nn], 0, 0, 0);                   \
      acc[Q2 * 2 + 1][nn] = __builtin_amdgcn_mfma_f32_16x16x32_bf16(         \
          aF1k1, bF[nn][1], acc[Q2 * 2 + 1][nn], 0, 0, 0);                   \
    }                                                                        \
    __builtin_amdgcn_s_setprio(0);                                           \
    __builtin_amdgcn_s_barrier();                                            \
  }

  // ---- prologue: tile0 complete + tile1's B; allow B(1) in flight ----
  STG_A0(0, 0); STG_A1(0, 0); STG_B0(0, 0); STG_B1(0, 0);
  STG_B0(1, 1); STG_B1(1, 1);
  VM4;
  __builtin_amdgcn_s_barrier();

  for (int t = 0; t < NT; t += 2) {
    const bool s2 = (t + 2) < NT, s3 = (t + 3) < NT;
    // P1..P4: tile t from buf0
    PHASE(0, 0, true,  VMNONE, { STG_A0(1, t + 1); });
    PHASE(1, 0, false, VMNONE, { STG_A1(1, t + 1); if (s2) STG_B0(0, t + 2); });
    PHASE(2, 0, false, VMNONE, { if (s2) STG_B1(0, t + 2); });
    if (s2) { PHASE(3, 0, false, VM4, {}); }
    else    { PHASE(3, 0, false, VM0, {}); }
    // P5..P8: tile t+1 from buf1
    PHASE(0, 65536, true,  VMNONE, { if (s2) STG_A0(0, t + 2); });
    PHASE(1, 65536, false, VMNONE, { if (s2) STG_A1(0, t + 2); if (s3) STG_B0(1, t + 3); });
    PHASE(2, 65536, false, VMNONE, { if (s3) STG_B1(1, t + 3); });
    PHASE(3, 65536, false, VM4, {});
  }

  // ---- epilogue: C/D layout col = lane&15, row = q*4 + v [m89] ----
  const int crow = iBase + wm * 128 + q * 4;
  const int ccol = jBase + wn * 64 + r;
#pragma unroll
  for (int m = 0; m < 8; ++m)
#pragma unroll
    for (int nn = 0; nn < 4; ++nn)
#pragma unroll
      for (int v = 0; v < 4; ++v)
        Cmat[(size_t)(crow + m * 16 + v) * M_PTS + (ccol + nn * 16)] =
            acc[m][nn][v];
}

extern "C" void kernel_launch(void* const* d_in, const int* in_sizes, int n_in,
                              void* d_out, int out_size, void* d_ws,
                              size_t ws_size, hipStream_t stream) {
  const float* x    = (const float*)d_in[0];
  const float* z    = (const float*)d_in[1];
  const float* chol = (const float*)d_in[2];
  float* out = (float*)d_out;

  __hip_bfloat16* Kbf = (__hip_bfloat16*)d_ws;                        // 64 MB
  __hip_bfloat16* Bt  = (__hip_bfloat16*)((char*)d_ws +
                        (size_t)N_PTS * M_PTS * sizeof(__hip_bfloat16)); // 8 MB

  laplace_k<<<dim3(N_PTS), 256, 0, stream>>>(x, z, Kbf);
  transpose_cast<<<dim3(M_PTS / 32, M_PTS / 32), dim3(32, 8), 0, stream>>>(
      chol, Bt);
  gemm_bf16_8ph<<<dim3(512), 512, 0, stream>>>(Kbf, Bt, out);
}